// Round 11
// baseline (330.174 us; speedup 1.0000x reference)
//
#include <hip/hip_runtime.h>

#define N_NODES 100000
#define IN_F 256
#define OUT_F 128
#define NB 782     // coarse buckets: bin = dst >> 7, 128 nodes per bucket
#define EPB 2048   // edges per sort block
#define LCAP2 3072 // fine_csr2 LDS staging capacity (bucket mean 2046, +22 sigma)

typedef float f32x4 __attribute__((ext_vector_type(4)));
typedef __bf16 bf16x8 __attribute__((ext_vector_type(8)));

// RNE pack of two fp32 -> packed bf16x2
__device__ inline unsigned cvt2_bf16(float a, float b) {
  unsigned ua = __float_as_uint(a), ub = __float_as_uint(b);
  ua = (ua + 0x7fffu + ((ua >> 16) & 1u)) >> 16;
  ub = (ub + 0x7fffu + ((ub >> 16) & 1u)) >> 16;
  return ua | (ub << 16);
}
__device__ inline unsigned short cvt1_bf16(float a) {
  unsigned ua = __float_as_uint(a);
  return (unsigned short)((ua + 0x7fffu + ((ua >> 16) & 1u)) >> 16);
}

// -------- W pre-transpose into MFMA-B-frag order, fp32 -> bf16 --------
__global__ __launch_bounds__(256) void transpose_w(const float* __restrict__ w,
                                                   uint4* __restrict__ wt) {
  int c = blockIdx.x * 256 + threadIdx.x;  // 4096 chunks
  int l = c & 63;
  int kt = (c >> 6) & 7;
  int nt = c >> 9;
  int n = nt * 16 + (l & 15);
  int kb = kt * 32 + ((l >> 4) & 3) * 8;
  unsigned d[4];
#pragma unroll
  for (int j = 0; j < 4; ++j) {
    float a = w[(size_t)(kb + 2 * j) * OUT_F + n];
    float b = w[(size_t)(kb + 2 * j + 1) * OUT_F + n];
    d[j] = cvt2_bf16(a, b);
  }
  wt[c] = make_uint4(d[0], d[1], d[2], d[3]);
}

// -------- fused: gemm tiles + per-block LDS bin-sort with COALESCED dump -----
__global__ __launch_bounds__(256) void gemm_sort(const float* __restrict__ x,
                                                 const uint4* __restrict__ wt,
                                                 unsigned short* __restrict__ sup,
                                                 const int* __restrict__ ei,
                                                 const float* __restrict__ ew,
                                                 unsigned short* __restrict__ lst,
                                                 int2* __restrict__ buf1,
                                                 int nedges, int nblk, int gblocks) {
  __shared__ __align__(16) char smem[32768];
  const int gid = blockIdx.x;
  const int t = threadIdx.x;

  int role, sub;
  int m = (gblocks < nblk) ? gblocks : nblk;
  if (gid < 2 * m) {
    role = gid & 1;
    sub = gid >> 1;
  } else if (nblk > gblocks) {
    role = 1;
    sub = gid - gblocks;
  } else {
    role = 0;
    sub = gid - nblk;
  }

  if (role == 1) {
    // ---- sort role ----
    int2* ebuf = (int2*)smem;               // 16384 B: 2048 recs
    int* hist = (int*)(smem + 16384);       // 784 ints
    int* scn = (int*)(smem + 19520);        // 784 ints
    int* tmp = (int*)(smem + 22656);        // 256 ints
    const int base = sub * EPB;
    const int nE = min(EPB, nedges - base);

    for (int i = t; i < NB; i += 256) hist[i] = 0;
    __syncthreads();
    int d8[8], ok8[8];
#pragma unroll
    for (int j = 0; j < 8; ++j) {
      int e = base + j * 256 + t;
      ok8[j] = e < nedges;
      d8[j] = ok8[j] ? ei[e] : 0;
      if (ok8[j]) atomicAdd(&hist[d8[j] >> 7], 1);  // LDS atomic
    }
    __syncthreads();
    // exclusive scan hist -> scn (chunked 256-scan with carry)
    int carry = 0;
    for (int c0 = 0; c0 < NB; c0 += 256) {
      int idx = c0 + t;
      int v = (idx < NB) ? hist[idx] : 0;
      tmp[t] = v;
      __syncthreads();
      for (int off = 1; off < 256; off <<= 1) {
        int xv = (t >= off) ? tmp[t - off] : 0;
        __syncthreads();
        tmp[t] += xv;
        __syncthreads();
      }
      if (idx < NB) scn[idx] = carry + tmp[t] - v;
      int nc = carry + tmp[255];
      __syncthreads();
      carry = nc;
    }
    // write lstart row (coalesced u16) + sentinel
    for (int i = t; i < NB; i += 256)
      lst[(size_t)sub * (NB + 2) + i] = (unsigned short)scn[i];
    if (t == 0) lst[(size_t)sub * (NB + 2) + NB] = (unsigned short)nE;
    // live counters = copy of exclusive offsets
    for (int i = t; i < NB; i += 256) hist[i] = scn[i];
    __syncthreads();
    // scatter recs into LDS buffer
#pragma unroll
    for (int j = 0; j < 8; ++j) {
      if (ok8[j]) {
        int e = base + j * 256 + t;
        int srcn = ei[nedges + e];
        float wv = ew[e];
        int pos = atomicAdd(&hist[d8[j] >> 7], 1);  // LDS atomic
        ebuf[pos] = make_int2((srcn << 7) | (d8[j] & 127), __float_as_int(wv));
      }
    }
    __syncthreads();
    // contiguous coalesced dump
    for (int i = t; i < nE; i += 256) buf1[(size_t)sub * EPB + i] = ebuf[i];
    return;
  }

  // ---- gemm role: support(bf16) = X @ W, 128x128 tile ----
  uint4* As = (uint4*)smem;            // 16 KB
  uint4* Bs = (uint4*)(smem + 16384);  // 16 KB
  const int lane = t & 63;
  const int wv = t >> 6;
  const int wm = wv >> 1, wn = wv & 1;
  const int row0 = sub * 128;

  f32x4 acc[4][4];
#pragma unroll
  for (int mi = 0; mi < 4; ++mi)
#pragma unroll
    for (int ni = 0; ni < 4; ++ni) acc[mi][ni] = (f32x4){0.f, 0.f, 0.f, 0.f};

  for (int it = 0; it < 4; ++it) {
    const int k0 = it * 64;
#pragma unroll
    for (int i = 0; i < 4; ++i) {
      int ci = i * 256 + t;
      int g = ci >> 6, l = ci & 63;
      int mrow = (g >> 1) * 16 + (l & 15);
      int k = k0 + (g & 1) * 32 + ((l >> 4) & 3) * 8;
      int row = row0 + mrow;
      if (row > N_NODES - 1) row = N_NODES - 1;
      const float* src = x + (size_t)row * IN_F + k;
      f32x4 v0 = *(const f32x4*)src;
      f32x4 v1 = *(const f32x4*)(src + 4);
      As[ci] = make_uint4(cvt2_bf16(v0.x, v0.y), cvt2_bf16(v0.z, v0.w),
                          cvt2_bf16(v1.x, v1.y), cvt2_bf16(v1.z, v1.w));
      Bs[ci] = wt[((g >> 1) * 8 + it * 2 + (g & 1)) * 64 + l];
    }
    __syncthreads();
#pragma unroll
    for (int ktl = 0; ktl < 2; ++ktl) {
      bf16x8 af[4], bfr[4];
#pragma unroll
      for (int mi = 0; mi < 4; ++mi)
        af[mi] = *(bf16x8*)&As[((wm * 4 + mi) * 2 + ktl) * 64 + lane];
#pragma unroll
      for (int ni = 0; ni < 4; ++ni)
        bfr[ni] = *(bf16x8*)&Bs[((wn * 4 + ni) * 2 + ktl) * 64 + lane];
#pragma unroll
      for (int mi = 0; mi < 4; ++mi)
#pragma unroll
        for (int ni = 0; ni < 4; ++ni)
          acc[mi][ni] = __builtin_amdgcn_mfma_f32_16x16x32_bf16(af[mi], bfr[ni],
                                                                acc[mi][ni], 0, 0, 0);
    }
    __syncthreads();
  }

  const int quad = lane >> 4, col = lane & 15;
#pragma unroll
  for (int mi = 0; mi < 4; ++mi) {
#pragma unroll
    for (int r = 0; r < 4; ++r) {
      int row = row0 + (wm * 4 + mi) * 16 + quad * 4 + r;
      if (row < N_NODES) {
#pragma unroll
        for (int ni = 0; ni < 4; ++ni)
          sup[(size_t)row * OUT_F + (wn * 4 + ni) * 16 + col] =
              cvt1_bf16(acc[mi][ni][r]);
      }
    }
  }
}

// -------- per-bin total: one block per bin, tree-reduce (r7 lesson) ---------
__global__ __launch_bounds__(256) void colsum(const unsigned short* __restrict__ lst,
                                              int* __restrict__ coltot, int nblk) {
  __shared__ int red[256];
  const int bin = blockIdx.x;
  const int t = threadIdx.x;
  int sum = 0;
  for (int s = t; s < nblk; s += 256) {
    int a = lst[(size_t)s * (NB + 2) + bin];
    int b = lst[(size_t)s * (NB + 2) + bin + 1];
    sum += b - a;
  }
  red[t] = sum;
  __syncthreads();
  for (int off = 128; off > 0; off >>= 1) {
    if (t < off) red[t] += red[t + off];
    __syncthreads();
  }
  if (t == 0) coltot[bin] = red[0];
}

// -------- in-place inclusive scan (coltot, n=NB<=1024, 1 block) --------------
__global__ __launch_bounds__(256) void scan1(int* __restrict__ a,
                                             int* __restrict__ bsum, int n) {
  __shared__ int s[256];
  const int t = threadIdx.x;
  const int base = blockIdx.x * 1024 + t * 4;
  int v0 = (base + 0 < n) ? a[base + 0] : 0;
  int v1 = (base + 1 < n) ? a[base + 1] : 0;
  int v2 = (base + 2 < n) ? a[base + 2] : 0;
  int v3 = (base + 3 < n) ? a[base + 3] : 0;
  v1 += v0; v2 += v1; v3 += v2;
  s[t] = v3;
  __syncthreads();
  for (int off = 1; off < 256; off <<= 1) {
    int xv = (t >= off) ? s[t - off] : 0;
    __syncthreads();
    s[t] += xv;
    __syncthreads();
  }
  int excl = (t == 0) ? 0 : s[t - 1];
  if (base + 0 < n) a[base + 0] = v0 + excl;
  if (base + 1 < n) a[base + 1] = v1 + excl;
  if (base + 2 < n) a[base + 2] = v2 + excl;
  if (base + 3 < n) a[base + 3] = v3 + excl;
  if (t == 255 && bsum) bsum[blockIdx.x] = s[255];
}

// -------- fine CSR: GATHER bin's runs, LDS sort, write CSR COALESCED --------
__global__ __launch_bounds__(256) void fine_csr2(const int2* __restrict__ buf1,
                                                 const unsigned short* __restrict__ lst,
                                                 const int* __restrict__ coltot,
                                                 int2* __restrict__ recs,
                                                 int* __restrict__ rowptr, int nblk) {
  __shared__ int2 stg[LCAP2];             // 24 KB
  __shared__ unsigned short sidx[LCAP2];  // 6 KB
  __shared__ unsigned short aoff[800];    // lstart[s][bin]
  __shared__ int soff[800];               // exclusive scan of run lens
  __shared__ int tmp[256];
  __shared__ int cnt[128], wp[128];
  const int bin = blockIdx.x;
  const int t = threadIdx.x;

  // lens + exclusive scan over s
  int carry = 0;
  for (int c0 = 0; c0 < nblk; c0 += 256) {
    int s = c0 + t;
    int a = 0, b = 0;
    if (s < nblk) {
      a = lst[(size_t)s * (NB + 2) + bin];
      b = lst[(size_t)s * (NB + 2) + bin + 1];
      aoff[s] = (unsigned short)a;
    }
    int v = b - a;
    tmp[t] = v;
    __syncthreads();
    for (int off = 1; off < 256; off <<= 1) {
      int xv = (t >= off) ? tmp[t - off] : 0;
      __syncthreads();
      tmp[t] += xv;
      __syncthreads();
    }
    if (s < nblk) soff[s] = carry + tmp[t] - v;
    int nc = carry + tmp[255];
    __syncthreads();
    carry = nc;
  }
  int nrec = carry;
  if (nrec > LCAP2) nrec = LCAP2;  // skew guard; never taken on this data
  // gather runs into LDS staging
  for (int s = t; s < nblk; s += 256) {
    int o = soff[s];
    int a = aoff[s];
    int l = (((s + 1) < nblk) ? soff[s + 1] : carry) - o;
    for (int k = 0; k < l; ++k) {
      int q = o + k;
      if (q < LCAP2) stg[q] = buf1[(size_t)s * EPB + a + k];
    }
  }
  if (t < 128) cnt[t] = 0;
  __syncthreads();
  // counting sort by dst&127
  for (int i = t; i < nrec; i += 256) atomicAdd(&cnt[stg[i].x & 127], 1);
  __syncthreads();
  for (int off = 1; off < 128; off <<= 1) {
    int xv = (t >= off && t < 128) ? cnt[t - off] : 0;
    __syncthreads();
    if (t < 128) cnt[t] += xv;
    __syncthreads();
  }
  const int segStart = bin ? coltot[bin - 1] : 0;
  if (t < 128) {
    wp[t] = (t == 0) ? 0 : cnt[t - 1];
    int node = bin * 128 + t;
    if (node < N_NODES) rowptr[node + 1] = segStart + cnt[t];
  }
  if (bin == 0 && t == 0) rowptr[0] = 0;
  __syncthreads();
  for (int i = t; i < nrec; i += 256) {
    int p = atomicAdd(&wp[stg[i].x & 127], 1);  // LDS atomic
    sidx[p] = (unsigned short)i;
  }
  __syncthreads();
  // coalesced dump in sorted order
  for (int q = t; q < nrec; q += 256) {
    int2 r = stg[sidx[q]];
    recs[segStart + q] = make_int2(r.x >> 7, r.y);
  }
}

// -------- aggregate v2: software-pipelined 8-wide, masked tail, nt streams --
// r9 diagnosis: v1 (4-wide, serial tail) was a dependent-chain latency kernel.
// v2: 8-wide chunks (2x MLP), next chunk's edge loads issued WHILE current
// chunk's sup gathers are in flight, masked tail, nt load/store on streaming
// recs/out. NT loads go through u64 alias (builtin rejects HIP vector types).
__global__ __launch_bounds__(256) void aggregate_bf16(const int* __restrict__ rowptr,
                                                      const int2* __restrict__ edges,
                                                      const unsigned short* __restrict__ sup,
                                                      float* __restrict__ out, int nnodes) {
  int wave = (int)((blockIdx.x * 256u + threadIdx.x) >> 6);
  int lane = threadIdx.x & 63;
  if (wave >= nnodes) return;
  int beg = rowptr[wave];
  int end = rowptr[wave + 1];
  float2 acc = make_float2(0.f, 0.f);
  const unsigned long long* e64 = (const unsigned long long*)edges;

  if (beg < end) {
    int s0, s1, s2, s3, s4, s5, s6, s7;
    int w0i, w1i, w2i, w3i, w4i, w5i, w6i, w7i;
    int t0, t1, t2, t3, t4, t5, t6, t7;
    int x0, x1, x2, x3, x4, x5, x6, x7;
#define LOADE(sv, wv, idx)                                                   \
  {                                                                          \
    int ii = (idx);                                                          \
    int cl = ii < end ? ii : end - 1;                                        \
    unsigned long long q = __builtin_nontemporal_load(e64 + cl);             \
    sv = (int)(unsigned)q;                                                   \
    wv = (ii < end) ? (int)(q >> 32) : 0;                                    \
  }
    LOADE(s0, w0i, beg + 0) LOADE(s1, w1i, beg + 1)
    LOADE(s2, w2i, beg + 2) LOADE(s3, w3i, beg + 3)
    LOADE(s4, w4i, beg + 4) LOADE(s5, w5i, beg + 5)
    LOADE(s6, w6i, beg + 6) LOADE(s7, w7i, beg + 7)
    for (int e = beg; e < end; e += 8) {
      // issue 8 independent sup gathers
      unsigned u0 = *(const unsigned*)(sup + (size_t)s0 * OUT_F + lane * 2);
      unsigned u1 = *(const unsigned*)(sup + (size_t)s1 * OUT_F + lane * 2);
      unsigned u2 = *(const unsigned*)(sup + (size_t)s2 * OUT_F + lane * 2);
      unsigned u3 = *(const unsigned*)(sup + (size_t)s3 * OUT_F + lane * 2);
      unsigned u4 = *(const unsigned*)(sup + (size_t)s4 * OUT_F + lane * 2);
      unsigned u5 = *(const unsigned*)(sup + (size_t)s5 * OUT_F + lane * 2);
      unsigned u6 = *(const unsigned*)(sup + (size_t)s6 * OUT_F + lane * 2);
      unsigned u7 = *(const unsigned*)(sup + (size_t)s7 * OUT_F + lane * 2);
      float w0 = __int_as_float(w0i), w1 = __int_as_float(w1i);
      float w2 = __int_as_float(w2i), w3 = __int_as_float(w3i);
      float w4 = __int_as_float(w4i), w5 = __int_as_float(w5i);
      float w6 = __int_as_float(w6i), w7 = __int_as_float(w7i);
      // prefetch next chunk's edges (overlaps sup-gather latency)
      int en = e + 8;
      if (en < end) {
        LOADE(t0, x0, en + 0) LOADE(t1, x1, en + 1)
        LOADE(t2, x2, en + 2) LOADE(t3, x3, en + 3)
        LOADE(t4, x4, en + 4) LOADE(t5, x5, en + 5)
        LOADE(t6, x6, en + 6) LOADE(t7, x7, en + 7)
      }
      acc.x = fmaf(__uint_as_float(u0 << 16), w0, acc.x);
      acc.y = fmaf(__uint_as_float(u0 & 0xffff0000u), w0, acc.y);
      acc.x = fmaf(__uint_as_float(u1 << 16), w1, acc.x);
      acc.y = fmaf(__uint_as_float(u1 & 0xffff0000u), w1, acc.y);
      acc.x = fmaf(__uint_as_float(u2 << 16), w2, acc.x);
      acc.y = fmaf(__uint_as_float(u2 & 0xffff0000u), w2, acc.y);
      acc.x = fmaf(__uint_as_float(u3 << 16), w3, acc.x);
      acc.y = fmaf(__uint_as_float(u3 & 0xffff0000u), w3, acc.y);
      acc.x = fmaf(__uint_as_float(u4 << 16), w4, acc.x);
      acc.y = fmaf(__uint_as_float(u4 & 0xffff0000u), w4, acc.y);
      acc.x = fmaf(__uint_as_float(u5 << 16), w5, acc.x);
      acc.y = fmaf(__uint_as_float(u5 & 0xffff0000u), w5, acc.y);
      acc.x = fmaf(__uint_as_float(u6 << 16), w6, acc.x);
      acc.y = fmaf(__uint_as_float(u6 & 0xffff0000u), w6, acc.y);
      acc.x = fmaf(__uint_as_float(u7 << 16), w7, acc.x);
      acc.y = fmaf(__uint_as_float(u7 & 0xffff0000u), w7, acc.y);
      s0 = t0; s1 = t1; s2 = t2; s3 = t3;
      s4 = t4; s5 = t5; s6 = t6; s7 = t7;
      w0i = x0; w1i = x1; w2i = x2; w3i = x3;
      w4i = x4; w5i = x5; w6i = x6; w7i = x7;
    }
#undef LOADE
  }
  unsigned long long pk = (unsigned long long)__float_as_uint(acc.x) |
                          ((unsigned long long)__float_as_uint(acc.y) << 32);
  __builtin_nontemporal_store(
      pk, (unsigned long long*)(out + (size_t)wave * OUT_F + lane * 2));
}

// -------- standalone gemm (fallback path only) --------
__global__ __launch_bounds__(256) void gemm_mfma(const float* __restrict__ x,
                                                 const uint4* __restrict__ wt,
                                                 unsigned short* __restrict__ sup) {
  __shared__ uint4 As[1024];
  __shared__ uint4 Bs[1024];
  const int t = threadIdx.x;
  const int lane = t & 63;
  const int wv = t >> 6;
  const int wm = wv >> 1, wn = wv & 1;
  const int row0 = blockIdx.x * 128;

  f32x4 acc[4][4];
#pragma unroll
  for (int mi = 0; mi < 4; ++mi)
#pragma unroll
    for (int ni = 0; ni < 4; ++ni) acc[mi][ni] = (f32x4){0.f, 0.f, 0.f, 0.f};

  for (int it = 0; it < 4; ++it) {
    const int k0 = it * 64;
#pragma unroll
    for (int i = 0; i < 4; ++i) {
      int ci = i * 256 + t;
      int g = ci >> 6, l = ci & 63;
      int m = (g >> 1) * 16 + (l & 15);
      int k = k0 + (g & 1) * 32 + ((l >> 4) & 3) * 8;
      int row = row0 + m;
      if (row > N_NODES - 1) row = N_NODES - 1;
      const float* src = x + (size_t)row * IN_F + k;
      f32x4 v0 = *(const f32x4*)src;
      f32x4 v1 = *(const f32x4*)(src + 4);
      As[ci] = make_uint4(cvt2_bf16(v0.x, v0.y), cvt2_bf16(v0.z, v0.w),
                          cvt2_bf16(v1.x, v1.y), cvt2_bf16(v1.z, v1.w));
      Bs[ci] = wt[((g >> 1) * 8 + it * 2 + (g & 1)) * 64 + l];
    }
    __syncthreads();
#pragma unroll
    for (int ktl = 0; ktl < 2; ++ktl) {
      bf16x8 af[4], bfr[4];
#pragma unroll
      for (int mi = 0; mi < 4; ++mi)
        af[mi] = *(bf16x8*)&As[((wm * 4 + mi) * 2 + ktl) * 64 + lane];
#pragma unroll
      for (int ni = 0; ni < 4; ++ni)
        bfr[ni] = *(bf16x8*)&Bs[((wn * 4 + ni) * 2 + ktl) * 64 + lane];
#pragma unroll
      for (int mi = 0; mi < 4; ++mi)
#pragma unroll
        for (int ni = 0; ni < 4; ++ni)
          acc[mi][ni] = __builtin_amdgcn_mfma_f32_16x16x32_bf16(af[mi], bfr[ni],
                                                                acc[mi][ni], 0, 0, 0);
    }
    __syncthreads();
  }

  const int quad = lane >> 4, col = lane & 15;
#pragma unroll
  for (int mi = 0; mi < 4; ++mi) {
#pragma unroll
    for (int r = 0; r < 4; ++r) {
      int row = row0 + (wm * 4 + mi) * 16 + quad * 4 + r;
      if (row < N_NODES) {
#pragma unroll
        for (int ni = 0; ni < 4; ++ni)
          sup[(size_t)row * OUT_F + (wn * 4 + ni) * 16 + col] =
              cvt1_bf16(acc[mi][ni][r]);
      }
    }
  }
}

// -------- fallback: atomic scatter (only if ws too small) --------
__global__ __launch_bounds__(256) void scatter_edges(const int* __restrict__ ei,
                                                     const float* __restrict__ ew,
                                                     const unsigned short* __restrict__ sup,
                                                     float* __restrict__ out, int nedges) {
  int gwave = (int)((blockIdx.x * 256u + threadIdx.x) >> 6);
  int lane = threadIdx.x & 63;
  if (gwave >= nedges) return;
  int dst = ei[gwave];
  int src = ei[nedges + gwave];
  float wgt = ew[gwave];
  unsigned u = *(const unsigned*)(sup + (size_t)src * OUT_F + lane * 2);
  float* op = out + (size_t)dst * OUT_F + lane * 2;
  atomicAdd(op, __uint_as_float(u << 16) * wgt);
  atomicAdd(op + 1, __uint_as_float(u & 0xffff0000u) * wgt);
}

extern "C" void kernel_launch(void* const* d_in, const int* in_sizes, int n_in,
                              void* d_out, int out_size, void* d_ws, size_t ws_size,
                              hipStream_t stream) {
  const float* x = (const float*)d_in[0];
  const int* ei = (const int*)d_in[1];      // [2, E] int32 flat: row0=dst, row1=src
  const float* ew = (const float*)d_in[2];  // [E]
  const float* w = (const float*)d_in[3];   // [256,128]
  float* out = (float*)d_out;
  const int nedges = in_sizes[2];
  const int nblk = (nedges + EPB - 1) / EPB;  // sort blocks

  // workspace layout (bytes), all offsets 16B-aligned
  const size_t off_support = 0;
  const size_t sz_support = (size_t)N_NODES * OUT_F * 2;     // 25,600,000 (bf16)
  const size_t off_rowptr = off_support + sz_support;        // 25,600,000
  const size_t off_wt = off_rowptr + 400016;                 // 26,000,016
  const size_t off_coltot = off_wt + 65536;                  // 26,065,552
  const size_t off_lst = off_coltot + 3152;                  // 26,068,704
  const size_t sz_lst = (size_t)nblk * (NB + 2) * 2;         // u16 offsets
  const size_t off_buf1 = (off_lst + sz_lst + 15) & ~(size_t)15;
  const size_t sz_buf1 = (size_t)nblk * EPB * 8;
  const size_t off_recs = off_buf1 + sz_buf1;
  const size_t total_ws = off_recs + (size_t)nedges * 8;     // ~52.9 MB @ E=1.6M

  unsigned short* support = (unsigned short*)((char*)d_ws + off_support);
  int* rowptr = (int*)((char*)d_ws + off_rowptr);
  uint4* wt = (uint4*)((char*)d_ws + off_wt);
  int* coltot = (int*)((char*)d_ws + off_coltot);
  unsigned short* lst = (unsigned short*)((char*)d_ws + off_lst);
  int2* buf1 = (int2*)((char*)d_ws + off_buf1);
  int2* recs = (int2*)((char*)d_ws + off_recs);

  transpose_w<<<16, 256, 0, stream>>>(w, wt);

  if (ws_size < total_ws || nblk > 800) {
    const int gblocks = (N_NODES + 127) / 128;
    gemm_mfma<<<gblocks, 256, 0, stream>>>(x, wt, support);
    hipMemsetAsync(d_out, 0, (size_t)out_size * sizeof(float), stream);
    int sblocks = (nedges + 3) / 4;
    scatter_edges<<<sblocks, 256, 0, stream>>>(ei, ew, support, out, nedges);
    return;
  }

  const int gblocks = (N_NODES + 127) / 128;  // 782 gemm tiles

  gemm_sort<<<gblocks + nblk, 256, 0, stream>>>(x, wt, support, ei, ew, lst,
                                                buf1, nedges, nblk, gblocks);
  colsum<<<NB, 256, 0, stream>>>(lst, coltot, nblk);
  scan1<<<1, 256, 0, stream>>>(coltot, (int*)nullptr, NB);
  fine_csr2<<<NB, 256, 0, stream>>>(buf1, lst, coltot, recs, rowptr, nblk);

  const int ablocks = (N_NODES + 3) / 4;
  aggregate_bf16<<<ablocks, 256, 0, stream>>>(rowptr, recs, support, out, N_NODES);
}

// Round 12
// 300.759 us; speedup vs baseline: 1.0978x; 1.0978x over previous
//
#include <hip/hip_runtime.h>

#define N_NODES 100000
#define IN_F 256
#define OUT_F 128
#define NB 782     // coarse buckets: bin = dst >> 7, 128 nodes per bucket
#define EPB 2048   // edges per sort block
#define LCAP2 3072 // fine_csr2 LDS staging capacity (bucket mean 2046, +22 sigma)

typedef float f32x4 __attribute__((ext_vector_type(4)));
typedef __bf16 bf16x8 __attribute__((ext_vector_type(8)));

// RNE pack of two fp32 -> packed bf16x2
__device__ inline unsigned cvt2_bf16(float a, float b) {
  unsigned ua = __float_as_uint(a), ub = __float_as_uint(b);
  ua = (ua + 0x7fffu + ((ua >> 16) & 1u)) >> 16;
  ub = (ub + 0x7fffu + ((ub >> 16) & 1u)) >> 16;
  return ua | (ub << 16);
}
__device__ inline unsigned short cvt1_bf16(float a) {
  unsigned ua = __float_as_uint(a);
  return (unsigned short)((ua + 0x7fffu + ((ua >> 16) & 1u)) >> 16);
}

// -------- W pre-transpose into MFMA-B-frag order, fp32 -> bf16 --------
__global__ __launch_bounds__(256) void transpose_w(const float* __restrict__ w,
                                                   uint4* __restrict__ wt) {
  int c = blockIdx.x * 256 + threadIdx.x;  // 4096 chunks
  int l = c & 63;
  int kt = (c >> 6) & 7;
  int nt = c >> 9;
  int n = nt * 16 + (l & 15);
  int kb = kt * 32 + ((l >> 4) & 3) * 8;
  unsigned d[4];
#pragma unroll
  for (int j = 0; j < 4; ++j) {
    float a = w[(size_t)(kb + 2 * j) * OUT_F + n];
    float b = w[(size_t)(kb + 2 * j + 1) * OUT_F + n];
    d[j] = cvt2_bf16(a, b);
  }
  wt[c] = make_uint4(d[0], d[1], d[2], d[3]);
}

// -------- fused: gemm tiles + per-block LDS bin-sort with COALESCED dump -----
__global__ __launch_bounds__(256) void gemm_sort(const float* __restrict__ x,
                                                 const uint4* __restrict__ wt,
                                                 unsigned short* __restrict__ sup,
                                                 const int* __restrict__ ei,
                                                 const float* __restrict__ ew,
                                                 unsigned short* __restrict__ lst,
                                                 int2* __restrict__ buf1,
                                                 int nedges, int nblk, int gblocks) {
  __shared__ __align__(16) char smem[32768];
  const int gid = blockIdx.x;
  const int t = threadIdx.x;

  int role, sub;
  int m = (gblocks < nblk) ? gblocks : nblk;
  if (gid < 2 * m) {
    role = gid & 1;
    sub = gid >> 1;
  } else if (nblk > gblocks) {
    role = 1;
    sub = gid - gblocks;
  } else {
    role = 0;
    sub = gid - nblk;
  }

  if (role == 1) {
    // ---- sort role ----
    int2* ebuf = (int2*)smem;               // 16384 B: 2048 recs
    int* hist = (int*)(smem + 16384);       // 784 ints
    int* scn = (int*)(smem + 19520);        // 784 ints
    int* tmp = (int*)(smem + 22656);        // 256 ints
    const int base = sub * EPB;
    const int nE = min(EPB, nedges - base);

    for (int i = t; i < NB; i += 256) hist[i] = 0;
    __syncthreads();
    int d8[8], ok8[8];
#pragma unroll
    for (int j = 0; j < 8; ++j) {
      int e = base + j * 256 + t;
      ok8[j] = e < nedges;
      d8[j] = ok8[j] ? ei[e] : 0;
      if (ok8[j]) atomicAdd(&hist[d8[j] >> 7], 1);  // LDS atomic
    }
    __syncthreads();
    // exclusive scan hist -> scn (chunked 256-scan with carry)
    int carry = 0;
    for (int c0 = 0; c0 < NB; c0 += 256) {
      int idx = c0 + t;
      int v = (idx < NB) ? hist[idx] : 0;
      tmp[t] = v;
      __syncthreads();
      for (int off = 1; off < 256; off <<= 1) {
        int xv = (t >= off) ? tmp[t - off] : 0;
        __syncthreads();
        tmp[t] += xv;
        __syncthreads();
      }
      if (idx < NB) scn[idx] = carry + tmp[t] - v;
      int nc = carry + tmp[255];
      __syncthreads();
      carry = nc;
    }
    // write lstart row (coalesced u16) + sentinel
    for (int i = t; i < NB; i += 256)
      lst[(size_t)sub * (NB + 2) + i] = (unsigned short)scn[i];
    if (t == 0) lst[(size_t)sub * (NB + 2) + NB] = (unsigned short)nE;
    // live counters = copy of exclusive offsets
    for (int i = t; i < NB; i += 256) hist[i] = scn[i];
    __syncthreads();
    // scatter recs into LDS buffer
#pragma unroll
    for (int j = 0; j < 8; ++j) {
      if (ok8[j]) {
        int e = base + j * 256 + t;
        int srcn = ei[nedges + e];
        float wv = ew[e];
        int pos = atomicAdd(&hist[d8[j] >> 7], 1);  // LDS atomic
        ebuf[pos] = make_int2((srcn << 7) | (d8[j] & 127), __float_as_int(wv));
      }
    }
    __syncthreads();
    // contiguous coalesced dump
    for (int i = t; i < nE; i += 256) buf1[(size_t)sub * EPB + i] = ebuf[i];
    return;
  }

  // ---- gemm role: support(bf16) = X @ W, 128x128 tile ----
  uint4* As = (uint4*)smem;            // 16 KB
  uint4* Bs = (uint4*)(smem + 16384);  // 16 KB
  const int lane = t & 63;
  const int wv = t >> 6;
  const int wm = wv >> 1, wn = wv & 1;
  const int row0 = sub * 128;

  f32x4 acc[4][4];
#pragma unroll
  for (int mi = 0; mi < 4; ++mi)
#pragma unroll
    for (int ni = 0; ni < 4; ++ni) acc[mi][ni] = (f32x4){0.f, 0.f, 0.f, 0.f};

  for (int it = 0; it < 4; ++it) {
    const int k0 = it * 64;
#pragma unroll
    for (int i = 0; i < 4; ++i) {
      int ci = i * 256 + t;
      int g = ci >> 6, l = ci & 63;
      int mrow = (g >> 1) * 16 + (l & 15);
      int k = k0 + (g & 1) * 32 + ((l >> 4) & 3) * 8;
      int row = row0 + mrow;
      if (row > N_NODES - 1) row = N_NODES - 1;
      const float* src = x + (size_t)row * IN_F + k;
      f32x4 v0 = *(const f32x4*)src;
      f32x4 v1 = *(const f32x4*)(src + 4);
      As[ci] = make_uint4(cvt2_bf16(v0.x, v0.y), cvt2_bf16(v0.z, v0.w),
                          cvt2_bf16(v1.x, v1.y), cvt2_bf16(v1.z, v1.w));
      Bs[ci] = wt[((g >> 1) * 8 + it * 2 + (g & 1)) * 64 + l];
    }
    __syncthreads();
#pragma unroll
    for (int ktl = 0; ktl < 2; ++ktl) {
      bf16x8 af[4], bfr[4];
#pragma unroll
      for (int mi = 0; mi < 4; ++mi)
        af[mi] = *(bf16x8*)&As[((wm * 4 + mi) * 2 + ktl) * 64 + lane];
#pragma unroll
      for (int ni = 0; ni < 4; ++ni)
        bfr[ni] = *(bf16x8*)&Bs[((wn * 4 + ni) * 2 + ktl) * 64 + lane];
#pragma unroll
      for (int mi = 0; mi < 4; ++mi)
#pragma unroll
        for (int ni = 0; ni < 4; ++ni)
          acc[mi][ni] = __builtin_amdgcn_mfma_f32_16x16x32_bf16(af[mi], bfr[ni],
                                                                acc[mi][ni], 0, 0, 0);
    }
    __syncthreads();
  }

  const int quad = lane >> 4, col = lane & 15;
#pragma unroll
  for (int mi = 0; mi < 4; ++mi) {
#pragma unroll
    for (int r = 0; r < 4; ++r) {
      int row = row0 + (wm * 4 + mi) * 16 + quad * 4 + r;
      if (row < N_NODES) {
#pragma unroll
        for (int ni = 0; ni < 4; ++ni)
          sup[(size_t)row * OUT_F + (wn * 4 + ni) * 16 + col] =
              cvt1_bf16(acc[mi][ni][r]);
      }
    }
  }
}

// -------- per-bin total: one block per bin, tree-reduce (r7 lesson) ---------
__global__ __launch_bounds__(256) void colsum(const unsigned short* __restrict__ lst,
                                              int* __restrict__ coltot, int nblk) {
  __shared__ int red[256];
  const int bin = blockIdx.x;
  const int t = threadIdx.x;
  int sum = 0;
  for (int s = t; s < nblk; s += 256) {
    int a = lst[(size_t)s * (NB + 2) + bin];
    int b = lst[(size_t)s * (NB + 2) + bin + 1];
    sum += b - a;
  }
  red[t] = sum;
  __syncthreads();
  for (int off = 128; off > 0; off >>= 1) {
    if (t < off) red[t] += red[t + off];
    __syncthreads();
  }
  if (t == 0) coltot[bin] = red[0];
}

// -------- in-place inclusive scan (coltot, n=NB<=1024, 1 block) --------------
__global__ __launch_bounds__(256) void scan1(int* __restrict__ a,
                                             int* __restrict__ bsum, int n) {
  __shared__ int s[256];
  const int t = threadIdx.x;
  const int base = blockIdx.x * 1024 + t * 4;
  int v0 = (base + 0 < n) ? a[base + 0] : 0;
  int v1 = (base + 1 < n) ? a[base + 1] : 0;
  int v2 = (base + 2 < n) ? a[base + 2] : 0;
  int v3 = (base + 3 < n) ? a[base + 3] : 0;
  v1 += v0; v2 += v1; v3 += v2;
  s[t] = v3;
  __syncthreads();
  for (int off = 1; off < 256; off <<= 1) {
    int xv = (t >= off) ? s[t - off] : 0;
    __syncthreads();
    s[t] += xv;
    __syncthreads();
  }
  int excl = (t == 0) ? 0 : s[t - 1];
  if (base + 0 < n) a[base + 0] = v0 + excl;
  if (base + 1 < n) a[base + 1] = v1 + excl;
  if (base + 2 < n) a[base + 2] = v2 + excl;
  if (base + 3 < n) a[base + 3] = v3 + excl;
  if (t == 255 && bsum) bsum[blockIdx.x] = s[255];
}

// -------- fine CSR: GATHER bin's runs, LDS sort, write CSR COALESCED --------
__global__ __launch_bounds__(256) void fine_csr2(const int2* __restrict__ buf1,
                                                 const unsigned short* __restrict__ lst,
                                                 const int* __restrict__ coltot,
                                                 int2* __restrict__ recs,
                                                 int* __restrict__ rowptr, int nblk) {
  __shared__ int2 stg[LCAP2];             // 24 KB
  __shared__ unsigned short sidx[LCAP2];  // 6 KB
  __shared__ unsigned short aoff[800];    // lstart[s][bin]
  __shared__ int soff[800];               // exclusive scan of run lens
  __shared__ int tmp[256];
  __shared__ int cnt[128], wp[128];
  const int bin = blockIdx.x;
  const int t = threadIdx.x;

  // lens + exclusive scan over s
  int carry = 0;
  for (int c0 = 0; c0 < nblk; c0 += 256) {
    int s = c0 + t;
    int a = 0, b = 0;
    if (s < nblk) {
      a = lst[(size_t)s * (NB + 2) + bin];
      b = lst[(size_t)s * (NB + 2) + bin + 1];
      aoff[s] = (unsigned short)a;
    }
    int v = b - a;
    tmp[t] = v;
    __syncthreads();
    for (int off = 1; off < 256; off <<= 1) {
      int xv = (t >= off) ? tmp[t - off] : 0;
      __syncthreads();
      tmp[t] += xv;
      __syncthreads();
    }
    if (s < nblk) soff[s] = carry + tmp[t] - v;
    int nc = carry + tmp[255];
    __syncthreads();
    carry = nc;
  }
  int nrec = carry;
  if (nrec > LCAP2) nrec = LCAP2;  // skew guard; never taken on this data
  // gather runs into LDS staging
  for (int s = t; s < nblk; s += 256) {
    int o = soff[s];
    int a = aoff[s];
    int l = (((s + 1) < nblk) ? soff[s + 1] : carry) - o;
    for (int k = 0; k < l; ++k) {
      int q = o + k;
      if (q < LCAP2) stg[q] = buf1[(size_t)s * EPB + a + k];
    }
  }
  if (t < 128) cnt[t] = 0;
  __syncthreads();
  // counting sort by dst&127
  for (int i = t; i < nrec; i += 256) atomicAdd(&cnt[stg[i].x & 127], 1);
  __syncthreads();
  for (int off = 1; off < 128; off <<= 1) {
    int xv = (t >= off && t < 128) ? cnt[t - off] : 0;
    __syncthreads();
    if (t < 128) cnt[t] += xv;
    __syncthreads();
  }
  const int segStart = bin ? coltot[bin - 1] : 0;
  if (t < 128) {
    wp[t] = (t == 0) ? 0 : cnt[t - 1];
    int node = bin * 128 + t;
    if (node < N_NODES) rowptr[node + 1] = segStart + cnt[t];
  }
  if (bin == 0 && t == 0) rowptr[0] = 0;
  __syncthreads();
  for (int i = t; i < nrec; i += 256) {
    int p = atomicAdd(&wp[stg[i].x & 127], 1);  // LDS atomic
    sidx[p] = (unsigned short)i;
  }
  __syncthreads();
  // coalesced dump in sorted order
  for (int q = t; q < nrec; q += 256) {
    int2 r = stg[sidx[q]];
    recs[segStart + q] = make_int2(r.x >> 7, r.y);
  }
}

// -------- aggregate v3: v1's exact 4-wide loop + depth-1 edge prefetch ------
// r11 post-mortem: v2's 8-wide masking cost 25% padded gathers + VALU masks +
// occupancy (97us vs v1's 74). v3 keeps v1's structure (no masking, no
// padding, scalar tail) and adds ONLY: next chunk's edge records prefetched
// into registers between gather-issue and fmafs (full chunks only), breaking
// the in-order chain fmaf(gather) -> next edge load. nt store on out (50MB
// write-once) keeps L2 capacity for sup rows.
__global__ __launch_bounds__(256) void aggregate_bf16(const int* __restrict__ rowptr,
                                                      const int2* __restrict__ edges,
                                                      const unsigned short* __restrict__ sup,
                                                      float* __restrict__ out, int nnodes) {
  int wave = (int)((blockIdx.x * 256u + threadIdx.x) >> 6);
  int lane = threadIdx.x & 63;
  if (wave >= nnodes) return;
  int beg = rowptr[wave];
  int end = rowptr[wave + 1];
  float2 acc = make_float2(0.f, 0.f);
  int e = beg;
  int2 m0 = make_int2(0, 0), m1 = m0, m2 = m0, m3 = m0;
  if (e + 4 <= end) {
    m0 = edges[e + 0];
    m1 = edges[e + 1];
    m2 = edges[e + 2];
    m3 = edges[e + 3];
  }
  for (; e + 4 <= end; e += 4) {
    unsigned u0 = *(const unsigned*)(sup + (size_t)m0.x * OUT_F + lane * 2);
    unsigned u1 = *(const unsigned*)(sup + (size_t)m1.x * OUT_F + lane * 2);
    unsigned u2 = *(const unsigned*)(sup + (size_t)m2.x * OUT_F + lane * 2);
    unsigned u3 = *(const unsigned*)(sup + (size_t)m3.x * OUT_F + lane * 2);
    float w0 = __int_as_float(m0.y), w1 = __int_as_float(m1.y);
    float w2 = __int_as_float(m2.y), w3 = __int_as_float(m3.y);
    int2 n0 = m0, n1 = m1, n2 = m2, n3 = m3;
    if (e + 8 <= end) {  // prefetch next full chunk (overlaps gather latency)
      n0 = edges[e + 4];
      n1 = edges[e + 5];
      n2 = edges[e + 6];
      n3 = edges[e + 7];
    }
    acc.x = fmaf(__uint_as_float(u0 << 16), w0, acc.x);
    acc.y = fmaf(__uint_as_float(u0 & 0xffff0000u), w0, acc.y);
    acc.x = fmaf(__uint_as_float(u1 << 16), w1, acc.x);
    acc.y = fmaf(__uint_as_float(u1 & 0xffff0000u), w1, acc.y);
    acc.x = fmaf(__uint_as_float(u2 << 16), w2, acc.x);
    acc.y = fmaf(__uint_as_float(u2 & 0xffff0000u), w2, acc.y);
    acc.x = fmaf(__uint_as_float(u3 << 16), w3, acc.x);
    acc.y = fmaf(__uint_as_float(u3 & 0xffff0000u), w3, acc.y);
    m0 = n0; m1 = n1; m2 = n2; m3 = n3;
  }
  for (; e < end; ++e) {
    int2 m = edges[e];
    unsigned u = *(const unsigned*)(sup + (size_t)m.x * OUT_F + lane * 2);
    float w = __int_as_float(m.y);
    acc.x = fmaf(__uint_as_float(u << 16), w, acc.x);
    acc.y = fmaf(__uint_as_float(u & 0xffff0000u), w, acc.y);
  }
  unsigned long long pk = (unsigned long long)__float_as_uint(acc.x) |
                          ((unsigned long long)__float_as_uint(acc.y) << 32);
  __builtin_nontemporal_store(
      pk, (unsigned long long*)(out + (size_t)wave * OUT_F + lane * 2));
}

// -------- standalone gemm (fallback path only) --------
__global__ __launch_bounds__(256) void gemm_mfma(const float* __restrict__ x,
                                                 const uint4* __restrict__ wt,
                                                 unsigned short* __restrict__ sup) {
  __shared__ uint4 As[1024];
  __shared__ uint4 Bs[1024];
  const int t = threadIdx.x;
  const int lane = t & 63;
  const int wv = t >> 6;
  const int wm = wv >> 1, wn = wv & 1;
  const int row0 = blockIdx.x * 128;

  f32x4 acc[4][4];
#pragma unroll
  for (int mi = 0; mi < 4; ++mi)
#pragma unroll
    for (int ni = 0; ni < 4; ++ni) acc[mi][ni] = (f32x4){0.f, 0.f, 0.f, 0.f};

  for (int it = 0; it < 4; ++it) {
    const int k0 = it * 64;
#pragma unroll
    for (int i = 0; i < 4; ++i) {
      int ci = i * 256 + t;
      int g = ci >> 6, l = ci & 63;
      int m = (g >> 1) * 16 + (l & 15);
      int k = k0 + (g & 1) * 32 + ((l >> 4) & 3) * 8;
      int row = row0 + m;
      if (row > N_NODES - 1) row = N_NODES - 1;
      const float* src = x + (size_t)row * IN_F + k;
      f32x4 v0 = *(const f32x4*)src;
      f32x4 v1 = *(const f32x4*)(src + 4);
      As[ci] = make_uint4(cvt2_bf16(v0.x, v0.y), cvt2_bf16(v0.z, v0.w),
                          cvt2_bf16(v1.x, v1.y), cvt2_bf16(v1.z, v1.w));
      Bs[ci] = wt[((g >> 1) * 8 + it * 2 + (g & 1)) * 64 + l];
    }
    __syncthreads();
#pragma unroll
    for (int ktl = 0; ktl < 2; ++ktl) {
      bf16x8 af[4], bfr[4];
#pragma unroll
      for (int mi = 0; mi < 4; ++mi)
        af[mi] = *(bf16x8*)&As[((wm * 4 + mi) * 2 + ktl) * 64 + lane];
#pragma unroll
      for (int ni = 0; ni < 4; ++ni)
        bfr[ni] = *(bf16x8*)&Bs[((wn * 4 + ni) * 2 + ktl) * 64 + lane];
#pragma unroll
      for (int mi = 0; mi < 4; ++mi)
#pragma unroll
        for (int ni = 0; ni < 4; ++ni)
          acc[mi][ni] = __builtin_amdgcn_mfma_f32_16x16x32_bf16(af[mi], bfr[ni],
                                                                acc[mi][ni], 0, 0, 0);
    }
    __syncthreads();
  }

  const int quad = lane >> 4, col = lane & 15;
#pragma unroll
  for (int mi = 0; mi < 4; ++mi) {
#pragma unroll
    for (int r = 0; r < 4; ++r) {
      int row = row0 + (wm * 4 + mi) * 16 + quad * 4 + r;
      if (row < N_NODES) {
#pragma unroll
        for (int ni = 0; ni < 4; ++ni)
          sup[(size_t)row * OUT_F + (wn * 4 + ni) * 16 + col] =
              cvt1_bf16(acc[mi][ni][r]);
      }
    }
  }
}

// -------- fallback: atomic scatter (only if ws too small) --------
__global__ __launch_bounds__(256) void scatter_edges(const int* __restrict__ ei,
                                                     const float* __restrict__ ew,
                                                     const unsigned short* __restrict__ sup,
                                                     float* __restrict__ out, int nedges) {
  int gwave = (int)((blockIdx.x * 256u + threadIdx.x) >> 6);
  int lane = threadIdx.x & 63;
  if (gwave >= nedges) return;
  int dst = ei[gwave];
  int src = ei[nedges + gwave];
  float wgt = ew[gwave];
  unsigned u = *(const unsigned*)(sup + (size_t)src * OUT_F + lane * 2);
  float* op = out + (size_t)dst * OUT_F + lane * 2;
  atomicAdd(op, __uint_as_float(u << 16) * wgt);
  atomicAdd(op + 1, __uint_as_float(u & 0xffff0000u) * wgt);
}

extern "C" void kernel_launch(void* const* d_in, const int* in_sizes, int n_in,
                              void* d_out, int out_size, void* d_ws, size_t ws_size,
                              hipStream_t stream) {
  const float* x = (const float*)d_in[0];
  const int* ei = (const int*)d_in[1];      // [2, E] int32 flat: row0=dst, row1=src
  const float* ew = (const float*)d_in[2];  // [E]
  const float* w = (const float*)d_in[3];   // [256,128]
  float* out = (float*)d_out;
  const int nedges = in_sizes[2];
  const int nblk = (nedges + EPB - 1) / EPB;  // sort blocks

  // workspace layout (bytes), all offsets 16B-aligned
  const size_t off_support = 0;
  const size_t sz_support = (size_t)N_NODES * OUT_F * 2;     // 25,600,000 (bf16)
  const size_t off_rowptr = off_support + sz_support;        // 25,600,000
  const size_t off_wt = off_rowptr + 400016;                 // 26,000,016
  const size_t off_coltot = off_wt + 65536;                  // 26,065,552
  const size_t off_lst = off_coltot + 3152;                  // 26,068,704
  const size_t sz_lst = (size_t)nblk * (NB + 2) * 2;         // u16 offsets
  const size_t off_buf1 = (off_lst + sz_lst + 15) & ~(size_t)15;
  const size_t sz_buf1 = (size_t)nblk * EPB * 8;
  const size_t off_recs = off_buf1 + sz_buf1;
  const size_t total_ws = off_recs + (size_t)nedges * 8;     // ~52.9 MB @ E=1.6M

  unsigned short* support = (unsigned short*)((char*)d_ws + off_support);
  int* rowptr = (int*)((char*)d_ws + off_rowptr);
  uint4* wt = (uint4*)((char*)d_ws + off_wt);
  int* coltot = (int*)((char*)d_ws + off_coltot);
  unsigned short* lst = (unsigned short*)((char*)d_ws + off_lst);
  int2* buf1 = (int2*)((char*)d_ws + off_buf1);
  int2* recs = (int2*)((char*)d_ws + off_recs);

  transpose_w<<<16, 256, 0, stream>>>(w, wt);

  if (ws_size < total_ws || nblk > 800) {
    const int gblocks = (N_NODES + 127) / 128;
    gemm_mfma<<<gblocks, 256, 0, stream>>>(x, wt, support);
    hipMemsetAsync(d_out, 0, (size_t)out_size * sizeof(float), stream);
    int sblocks = (nedges + 3) / 4;
    scatter_edges<<<sblocks, 256, 0, stream>>>(ei, ew, support, out, nedges);
    return;
  }

  const int gblocks = (N_NODES + 127) / 128;  // 782 gemm tiles

  gemm_sort<<<gblocks + nblk, 256, 0, stream>>>(x, wt, support, ei, ew, lst,
                                                buf1, nedges, nblk, gblocks);
  colsum<<<NB, 256, 0, stream>>>(lst, coltot, nblk);
  scan1<<<1, 256, 0, stream>>>(coltot, (int*)nullptr, NB);
  fine_csr2<<<NB, 256, 0, stream>>>(buf1, lst, coltot, recs, rowptr, nblk);

  const int ablocks = (N_NODES + 3) / 4;
  aggregate_bf16<<<ablocks, 256, 0, stream>>>(rowptr, recs, support, out, N_NODES);
}